// Round 1
// baseline (532.552 us; speedup 1.0000x reference)
//
#include <hip/hip_runtime.h>

// AdjointODE: h_{s+1} = h_s + dt_s * ( tanh(h_s@W1 + b1) @ W2 + b2 )
// BATCH=32768, DIM=128, HID=256, NSTEPS=50.
// One persistent kernel: 256 blocks x 256 threads (4 waves), block owns 128 rows.
// Weights bf16 in LDS (transposed, B-frag layout); h fp32 in registers (MFMA
// C-layout); activations round-trip through an 18KB LDS buffer in 64-hid chunks.
// Matmul2 accumulates directly into h (act pre-scaled by dt).

typedef __attribute__((ext_vector_type(8))) short short8;   // 8 bf16 = 4 VGPRs
typedef __attribute__((ext_vector_type(4))) float float4v;  // 4 fp32 acc

// LDS strides in shorts; rows 16B-aligned for ds_read_b128
#define W1_STRIDE 136   // 128 k + 8 pad   (272 B/row)
#define W2_STRIDE 264   // 256 k + 8 pad   (528 B/row)
#define BUF_STRIDE 72   // 64 cols + 8 pad (144 B/row)
#define W1_OFF 0
#define W2_OFF (256 * W1_STRIDE)                 // 34816
#define BUF_OFF (W2_OFF + 128 * W2_STRIDE)       // 68608
#define LDS_SHORTS (BUF_OFF + 128 * BUF_STRIDE)  // 77824 shorts = 155648 B

__device__ __forceinline__ unsigned short bf16_rne(float x) {
  unsigned int u = __float_as_uint(x);
  u += 0x7fffu + ((u >> 16) & 1u);
  return (unsigned short)(u >> 16);
}

__device__ __forceinline__ float tanh_fast(float x) {
  // tanh(x) = (e^{2x}-1)/(e^{2x}+1), clamped to avoid inf*0
  x = fminf(fmaxf(x, -9.0f), 9.0f);
  float e = __expf(2.0f * x);
  return (e - 1.0f) * __builtin_amdgcn_rcpf(e + 1.0f);
}

extern "C" __global__ __launch_bounds__(256, 1)
void ode_kernel(const float* __restrict__ inp, const float* __restrict__ ts,
                const float* __restrict__ W1, const float* __restrict__ b1,
                const float* __restrict__ W2, const float* __restrict__ b2,
                float* __restrict__ out) {
  __shared__ unsigned short lds[LDS_SHORTS];
  unsigned short* w1t = lds + W1_OFF;   // w1t[n][k]  n=hid 0..255, k=dim 0..127
  unsigned short* w2t = lds + W2_OFF;   // w2t[n2][k2] n2=dim 0..127, k2=hid 0..255
  unsigned short* buf = lds + BUF_OFF;  // [128 rows][64 cols] bf16 scratch

  const int tid  = threadIdx.x;
  const int wave = tid >> 6;
  const int lane = tid & 63;
  const int ln   = lane & 15;  // tile column index (n / A-row m)
  const int q    = lane >> 4;  // quad

  // ---- stage weights (transposed, k contiguous) ----
  for (int idx = tid; idx < 128 * 256; idx += 256) {
    int k = idx >> 8, n = idx & 255;         // W1[k][n], n contiguous
    w1t[n * W1_STRIDE + k] = bf16_rne(W1[idx]);
  }
  for (int idx = tid; idx < 256 * 128; idx += 256) {
    int k2 = idx >> 7, n2 = idx & 127;       // W2[k2][n2], n2 contiguous
    w2t[n2 * W2_STRIDE + k2] = bf16_rne(W2[idx]);
  }

  // ---- biases in per-lane registers (C-layout columns) ----
  float b1v[16], b2v[8];
  #pragma unroll
  for (int nt = 0; nt < 16; nt++) b1v[nt] = b1[nt * 16 + ln];
  #pragma unroll
  for (int t = 0; t < 8; t++) b2v[t] = b2[t * 16 + ln];

  // ---- load h into fp32 registers, MFMA C-layout ----
  // h[i][t][r]: row = rowbase + i*16 + q*4 + r, col = t*16 + ln
  float4v h[2][8];
  const int rowbase = blockIdx.x * 128 + wave * 32;
  #pragma unroll
  for (int i = 0; i < 2; i++)
    #pragma unroll
    for (int t = 0; t < 8; t++)
      #pragma unroll
      for (int r = 0; r < 4; r++)
        h[i][t][r] = inp[(rowbase + i * 16 + q * 4 + r) * 128 + t * 16 + ln];

  __syncthreads();  // weights staged

  #pragma unroll 1
  for (int s = 0; s < 50; s++) {
    float dt = ts[s + 1] - ts[s];

    // ---- phase 1: h (C-layout regs) -> bf16 A-frags via LDS, 2 col-chunks ----
    short8 ha[2][4];  // [m-tile][k-tile], k = ktile*32 + q*8 + j
    #pragma unroll
    for (int c = 0; c < 2; c++) {
      __syncthreads();  // buf free (previous readers done)
      #pragma unroll
      for (int i = 0; i < 2; i++)
        #pragma unroll
        for (int tl = 0; tl < 4; tl++)
          #pragma unroll
          for (int r = 0; r < 4; r++) {
            int row = wave * 32 + i * 16 + q * 4 + r;
            buf[row * BUF_STRIDE + tl * 16 + ln] = bf16_rne(h[i][c * 4 + tl][r]);
          }
      __syncthreads();
      #pragma unroll
      for (int i = 0; i < 2; i++)
        #pragma unroll
        for (int ktl = 0; ktl < 2; ktl++) {
          int row = wave * 32 + i * 16 + ln;
          ha[i][c * 2 + ktl] =
              *(const short8*)&buf[row * BUF_STRIDE + ktl * 32 + q * 8];
        }
    }

    // ---- phase 2: 4 hid-chunks of 64: G = h@W1, act = dt*tanh(G+b1),
    //      h += act@W2 (MFMA accumulates straight into h) ----
    #pragma unroll
    for (int c2 = 0; c2 < 4; c2++) {
      float4v g[2][4];
      #pragma unroll
      for (int i = 0; i < 2; i++)
        #pragma unroll
        for (int ntl = 0; ntl < 4; ntl++) g[i][ntl] = (float4v){0, 0, 0, 0};

      #pragma unroll
      for (int ntl = 0; ntl < 4; ntl++) {
        int n = (c2 * 4 + ntl) * 16 + ln;
        #pragma unroll
        for (int kt = 0; kt < 4; kt++) {
          short8 w = *(const short8*)&w1t[n * W1_STRIDE + kt * 32 + q * 8];
          g[0][ntl] = __builtin_amdgcn_mfma_f32_16x16x32_bf16(ha[0][kt], w, g[0][ntl], 0, 0, 0);
          g[1][ntl] = __builtin_amdgcn_mfma_f32_16x16x32_bf16(ha[1][kt], w, g[1][ntl], 0, 0, 0);
        }
      }

      __syncthreads();  // previous buf readers done
      #pragma unroll
      for (int i = 0; i < 2; i++)
        #pragma unroll
        for (int ntl = 0; ntl < 4; ntl++) {
          float bias = b1v[c2 * 4 + ntl];
          #pragma unroll
          for (int r = 0; r < 4; r++) {
            float a = tanh_fast(g[i][ntl][r] + bias) * dt;
            int row = wave * 32 + i * 16 + q * 4 + r;
            buf[row * BUF_STRIDE + ntl * 16 + ln] = bf16_rne(a);
          }
        }
      __syncthreads();

      short8 aa[2][2];
      #pragma unroll
      for (int i = 0; i < 2; i++)
        #pragma unroll
        for (int ktl = 0; ktl < 2; ktl++) {
          int row = wave * 32 + i * 16 + ln;
          aa[i][ktl] = *(const short8*)&buf[row * BUF_STRIDE + ktl * 32 + q * 8];
        }

      #pragma unroll
      for (int nt2 = 0; nt2 < 8; nt2++) {
        int n2 = nt2 * 16 + ln;
        #pragma unroll
        for (int ktl = 0; ktl < 2; ktl++) {
          short8 w = *(const short8*)&w2t[n2 * W2_STRIDE + (c2 * 2 + ktl) * 32 + q * 8];
          h[0][nt2] = __builtin_amdgcn_mfma_f32_16x16x32_bf16(aa[0][ktl], w, h[0][nt2], 0, 0, 0);
          h[1][nt2] = __builtin_amdgcn_mfma_f32_16x16x32_bf16(aa[1][ktl], w, h[1][nt2], 0, 0, 0);
        }
      }
    }

    // ---- h += dt * b2 ----
    #pragma unroll
    for (int i = 0; i < 2; i++)
      #pragma unroll
      for (int t = 0; t < 8; t++)
        #pragma unroll
        for (int r = 0; r < 4; r++) h[i][t][r] += dt * b2v[t];
  }

  // ---- store final h ----
  #pragma unroll
  for (int i = 0; i < 2; i++)
    #pragma unroll
    for (int t = 0; t < 8; t++)
      #pragma unroll
      for (int r = 0; r < 4; r++)
        out[(rowbase + i * 16 + q * 4 + r) * 128 + t * 16 + ln] = h[i][t][r];
}

extern "C" void kernel_launch(void* const* d_in, const int* in_sizes, int n_in,
                              void* d_out, int out_size, void* d_ws, size_t ws_size,
                              hipStream_t stream) {
  const float* inp = (const float*)d_in[0];
  const float* ts  = (const float*)d_in[1];
  const float* W1  = (const float*)d_in[2];
  const float* b1  = (const float*)d_in[3];
  const float* W2  = (const float*)d_in[4];
  const float* b2  = (const float*)d_in[5];
  hipLaunchKernelGGL(ode_kernel, dim3(256), dim3(256), 0, stream,
                     inp, ts, W1, b1, W2, b2, (float*)d_out);
}